// Round 1
// baseline (604.919 us; speedup 1.0000x reference)
//
#include <hip/hip_runtime.h>

#define C_IN 128
#define C_OUT 64
#define BN_EPS 1e-5f
#define LEAKY 0.01f

// ---------------------------------------------------------------------------
// K1: in-degree via atomics. deg[col[e]] += 1 for each edge (self-loop added
// later as +1 in k_dis).
__global__ __launch_bounds__(256) void k_degree(const int* __restrict__ col,
                                                int* __restrict__ deg, int nE) {
    int i = blockIdx.x * 256 + threadIdx.x;
    if (i < nE) atomicAdd(&deg[col[i]], 1);
}

// K2: dis[i] = rsqrt(deg[i] + 1)   (+1 = self loop; deg >= 1 always)
__global__ __launch_bounds__(256) void k_dis(const int* __restrict__ deg,
                                             float* __restrict__ dis, int n) {
    int i = blockIdx.x * 256 + threadIdx.x;
    if (i < n) dis[i] = rsqrtf((float)(deg[i] + 1));
}

// ---------------------------------------------------------------------------
// K3: xw = x @ W.  fp32, vector ALU (no fp32 MFMA on CDNA4).
// Block = 256 threads, 32 nodes/block. W staged in LDS [k][c] (32 KB),
// x tile staged in LDS with stride 132 (pad 4 floats keeps float4 alignment
// node*132*4=node*528, 528%16==0, and breaks the stride-128 bank pattern).
// Thread (cg4 = (t>>4)*4 channels, ng = t&15): computes nodes {ng, ng+16},
// 4 channels each => 8 accumulators, k unrolled by 4 with float4 LDS reads.
#define GEMM_NODES 32
#define XS_STRIDE 132
__global__ __launch_bounds__(256) void k_gemm(const float* __restrict__ x,
                                              const float* __restrict__ W,
                                              float* __restrict__ xw, int n) {
    __shared__ float Ws[C_IN * C_OUT];            // 32 KB
    __shared__ float xs[GEMM_NODES * XS_STRIDE];  // 16.5 KB

    const int t = threadIdx.x;
    const int base = blockIdx.x * GEMM_NODES;

    // load W (2048 float4, 8 per thread)
    {
        const float4* W4 = (const float4*)W;
        float4* Ws4 = (float4*)Ws;
        #pragma unroll
        for (int j = 0; j < 8; ++j) Ws4[t + j * 256] = W4[t + j * 256];
    }
    // load 32 x-rows (1024 float4, 4 per thread) into padded xs
    {
        const float4* x4 = (const float4*)x;
        #pragma unroll
        for (int j = 0; j < 4; ++j) {
            int i4 = t + j * 256;         // [0,1024)
            int node = i4 >> 5;           // [0,32)
            int kf = i4 & 31;             // float4 index within row
            float4 v = make_float4(0.f, 0.f, 0.f, 0.f);
            if (base + node < n) v = x4[(size_t)(base + node) * 32 + kf];
            *(float4*)&xs[node * XS_STRIDE + kf * 4] = v;
        }
    }
    __syncthreads();

    const int cg4 = (t >> 4) * 4;  // channel base {0,4,...,60}
    const int ng  = t & 15;        // local node {0..15}; handles ng, ng+16

    float acc[2][4] = {};
    #pragma unroll 8
    for (int k = 0; k < C_IN; k += 4) {
        float4 w0 = *(const float4*)&Ws[(k + 0) * C_OUT + cg4];
        float4 w1 = *(const float4*)&Ws[(k + 1) * C_OUT + cg4];
        float4 w2 = *(const float4*)&Ws[(k + 2) * C_OUT + cg4];
        float4 w3 = *(const float4*)&Ws[(k + 3) * C_OUT + cg4];
        #pragma unroll
        for (int j = 0; j < 2; ++j) {
            float4 xv = *(const float4*)&xs[(ng + 16 * j) * XS_STRIDE + k];
            acc[j][0] += xv.x * w0.x + xv.y * w1.x + xv.z * w2.x + xv.w * w3.x;
            acc[j][1] += xv.x * w0.y + xv.y * w1.y + xv.z * w2.y + xv.w * w3.y;
            acc[j][2] += xv.x * w0.z + xv.y * w1.z + xv.z * w2.z + xv.w * w3.z;
            acc[j][3] += xv.x * w0.w + xv.y * w1.w + xv.z * w2.w + xv.w * w3.w;
        }
    }
    #pragma unroll
    for (int j = 0; j < 2; ++j) {
        int node = base + ng + 16 * j;
        if (node < n)
            *(float4*)&xw[(size_t)node * C_OUT + cg4] =
                make_float4(acc[j][0], acc[j][1], acc[j][2], acc[j][3]);
    }
}

// ---------------------------------------------------------------------------
// K4: scatter-aggregate. One wave (64 lanes = 64 channels) per work item.
// Items [0,nE) are edges; [nE, total) are self-loops (row=col=i, norm=dis^2).
// agg[col][c] += xw[row][c] * dis[row] * dis[col]
__global__ __launch_bounds__(256) void k_scatter(const int* __restrict__ rows,
                                                 const int* __restrict__ cols,
                                                 const float* __restrict__ dis,
                                                 const float* __restrict__ xw,
                                                 float* __restrict__ agg,
                                                 int nE, int total) {
    int c = threadIdx.x & 63;
    int e = blockIdx.x * 4 + (threadIdx.x >> 6);
    if (e >= total) return;
    int r, cl;
    if (e < nE) { r = rows[e]; cl = cols[e]; }
    else        { r = e - nE; cl = r; }
    float nrm = dis[r] * dis[cl];
    float v = xw[(size_t)r * C_OUT + c] * nrm;
    atomicAdd(&agg[(size_t)cl * C_OUT + c], v);
}

// ---------------------------------------------------------------------------
// K5: per-channel sum and sum-of-squares over all nodes.
// stats[0..63] = sum, stats[64..127] = sumsq
__global__ __launch_bounds__(256) void k_stats(const float* __restrict__ agg,
                                               float* __restrict__ stats, int n) {
    int c = threadIdx.x & 63;
    int sub = threadIdx.x >> 6;  // 0..3
    float s = 0.f, s2 = 0.f;
    for (int node = blockIdx.x * 4 + sub; node < n; node += gridDim.x * 4) {
        float v = agg[(size_t)node * C_OUT + c];
        s += v;
        s2 += v * v;
    }
    __shared__ float red[2][4][64];
    red[0][sub][c] = s;
    red[1][sub][c] = s2;
    __syncthreads();
    if (sub == 0) {
        s  = red[0][0][c] + red[0][1][c] + red[0][2][c] + red[0][3][c];
        s2 = red[1][0][c] + red[1][1][c] + red[1][2][c] + red[1][3][c];
        atomicAdd(&stats[c], s);
        atomicAdd(&stats[64 + c], s2);
    }
}

// ---------------------------------------------------------------------------
// K6: BN normalize + LeakyReLU, float4, in-place on d_out.
// Note: GCN bias b cancels exactly in BatchNorm (out - mean), so it is never
// applied anywhere.
__global__ __launch_bounds__(256) void k_final(const float* __restrict__ stats,
                                               const float* __restrict__ gamma,
                                               const float* __restrict__ beta,
                                               float* __restrict__ out, int n) {
    int gid = blockIdx.x * 256 + threadIdx.x;
    int total4 = n * (C_OUT / 4);
    if (gid >= total4) return;
    int c4 = (gid & 15) * 4;
    float inv_n = 1.0f / (float)n;
    float4 s  = *(const float4*)&stats[c4];
    float4 s2 = *(const float4*)&stats[64 + c4];
    float4 g4 = *(const float4*)&gamma[c4];
    float4 b4 = *(const float4*)&beta[c4];
    float4 v = ((const float4*)out)[gid];

    float m, var, k, y;
    m = s.x * inv_n; var = s2.x * inv_n - m * m; k = rsqrtf(var + BN_EPS) * g4.x;
    y = (v.x - m) * k + b4.x; v.x = y >= 0.f ? y : LEAKY * y;
    m = s.y * inv_n; var = s2.y * inv_n - m * m; k = rsqrtf(var + BN_EPS) * g4.y;
    y = (v.y - m) * k + b4.y; v.y = y >= 0.f ? y : LEAKY * y;
    m = s.z * inv_n; var = s2.z * inv_n - m * m; k = rsqrtf(var + BN_EPS) * g4.z;
    y = (v.z - m) * k + b4.z; v.z = y >= 0.f ? y : LEAKY * y;
    m = s.w * inv_n; var = s2.w * inv_n - m * m; k = rsqrtf(var + BN_EPS) * g4.w;
    y = (v.w - m) * k + b4.w; v.w = y >= 0.f ? y : LEAKY * y;

    ((float4*)out)[gid] = v;
}

// ---------------------------------------------------------------------------
extern "C" void kernel_launch(void* const* d_in, const int* in_sizes, int n_in,
                              void* d_out, int out_size, void* d_ws, size_t ws_size,
                              hipStream_t stream) {
    const float* x     = (const float*)d_in[0];
    const int*   ei    = (const int*)d_in[1];
    const float* W     = (const float*)d_in[2];
    // d_in[3] = b: cancels in BatchNorm, unused.
    const float* gamma = (const float*)d_in[4];
    const float* beta  = (const float*)d_in[5];
    float* out = (float*)d_out;

    int n  = in_sizes[0] / C_IN;
    int nE = in_sizes[1] / 2;
    const int* rows = ei;
    const int* cols = ei + nE;

    // ws layout (float units): deg[n](int) | dis[n] | xw[n*64] | stats[128]
    int*   deg   = (int*)d_ws;
    float* dis   = (float*)d_ws + n;
    float* xw    = (float*)d_ws + 2 * (size_t)n;
    float* stats = (float*)d_ws + (size_t)(2 + C_OUT) * n;

    hipMemsetAsync(deg, 0, (size_t)n * sizeof(int), stream);
    hipMemsetAsync(out, 0, (size_t)n * C_OUT * sizeof(float), stream);
    hipMemsetAsync(stats, 0, 2 * C_OUT * sizeof(float), stream);

    k_degree<<<(nE + 255) / 256, 256, 0, stream>>>(cols, deg, nE);
    k_dis<<<(n + 255) / 256, 256, 0, stream>>>(deg, dis, n);
    k_gemm<<<(n + GEMM_NODES - 1) / GEMM_NODES, 256, 0, stream>>>(x, W, xw, n);

    int total = nE + n;  // edges + self-loops
    k_scatter<<<(total + 3) / 4, 256, 0, stream>>>(rows, cols, dis, xw, out, nE, total);

    k_stats<<<512, 256, 0, stream>>>(out, stats, n);
    k_final<<<(n * (C_OUT / 4) + 255) / 256, 256, 0, stream>>>(stats, gamma, beta, out, n);
}

// Round 3
// 425.383 us; speedup vs baseline: 1.4221x; 1.4221x over previous
//
#include <hip/hip_runtime.h>

#define C_IN 128
#define C_OUT 64
#define BN_EPS 1e-5f
#define LEAKY 0.01f

// ---------------------------------------------------------------------------
// K1: in-degree via atomics (edges only; self-loop handled as +1 in k_dis).
__global__ __launch_bounds__(256) void k_degree(const int* __restrict__ col,
                                                int* __restrict__ deg, int nE) {
    int i = blockIdx.x * 256 + threadIdx.x;
    if (i < nE) atomicAdd(&deg[col[i]], 1);
}

// K2: dis[i] = rsqrt(deg[i] + 1)
__global__ __launch_bounds__(256) void k_dis(const int* __restrict__ deg,
                                             float* __restrict__ dis, int n) {
    int i = blockIdx.x * 256 + threadIdx.x;
    if (i < n) dis[i] = rsqrtf((float)(deg[i] + 1));
}

// ---------------------------------------------------------------------------
// K3: xws = (x @ W) * dis[node]   (prescale folds dis[row] out of the gather
// inner loop). fp32 vector ALU (no fp32 MFMA on CDNA4).
#define GEMM_NODES 32
#define XS_STRIDE 132
__global__ __launch_bounds__(256) void k_gemm(const float* __restrict__ x,
                                              const float* __restrict__ W,
                                              const float* __restrict__ dis,
                                              float* __restrict__ xws, int n) {
    __shared__ float Ws[C_IN * C_OUT];            // 32 KB
    __shared__ float xs[GEMM_NODES * XS_STRIDE];  // 16.5 KB

    const int t = threadIdx.x;
    const int base = blockIdx.x * GEMM_NODES;

    {
        const float4* W4 = (const float4*)W;
        float4* Ws4 = (float4*)Ws;
        #pragma unroll
        for (int j = 0; j < 8; ++j) Ws4[t + j * 256] = W4[t + j * 256];
    }
    {
        const float4* x4 = (const float4*)x;
        #pragma unroll
        for (int j = 0; j < 4; ++j) {
            int i4 = t + j * 256;
            int node = i4 >> 5;
            int kf = i4 & 31;
            float4 v = make_float4(0.f, 0.f, 0.f, 0.f);
            if (base + node < n) v = x4[(size_t)(base + node) * 32 + kf];
            *(float4*)&xs[node * XS_STRIDE + kf * 4] = v;
        }
    }
    __syncthreads();

    const int cg4 = (t >> 4) * 4;
    const int ng  = t & 15;

    float acc[2][4] = {};
    #pragma unroll 8
    for (int k = 0; k < C_IN; k += 4) {
        float4 w0 = *(const float4*)&Ws[(k + 0) * C_OUT + cg4];
        float4 w1 = *(const float4*)&Ws[(k + 1) * C_OUT + cg4];
        float4 w2 = *(const float4*)&Ws[(k + 2) * C_OUT + cg4];
        float4 w3 = *(const float4*)&Ws[(k + 3) * C_OUT + cg4];
        #pragma unroll
        for (int j = 0; j < 2; ++j) {
            float4 xv = *(const float4*)&xs[(ng + 16 * j) * XS_STRIDE + k];
            acc[j][0] += xv.x * w0.x + xv.y * w1.x + xv.z * w2.x + xv.w * w3.x;
            acc[j][1] += xv.x * w0.y + xv.y * w1.y + xv.z * w2.y + xv.w * w3.y;
            acc[j][2] += xv.x * w0.z + xv.y * w1.z + xv.z * w2.z + xv.w * w3.z;
            acc[j][3] += xv.x * w0.w + xv.y * w1.w + xv.z * w2.w + xv.w * w3.w;
        }
    }
    #pragma unroll
    for (int j = 0; j < 2; ++j) {
        int node = base + ng + 16 * j;
        if (node < n) {
            float dn = dis[node];
            *(float4*)&xws[(size_t)node * C_OUT + cg4] =
                make_float4(acc[j][0] * dn, acc[j][1] * dn,
                            acc[j][2] * dn, acc[j][3] * dn);
        }
    }
}

// ---------------------------------------------------------------------------
// CSR build: exclusive scan of deg → ptr (starts), then counting-sort fill
// mutates ptr into segment ENDS (start = end - deg).

// K4a: per-block (1024 elems) scan. excl gets within-block exclusive scan,
// bsum[b] = block total.
__global__ __launch_bounds__(256) void k_scan_block(const int* __restrict__ deg,
                                                    int* __restrict__ excl,
                                                    int* __restrict__ bsum, int n) {
    __shared__ int s[256];
    int t = threadIdx.x;
    int base = blockIdx.x * 1024 + t * 4;
    int v0 = 0, v1 = 0, v2 = 0, v3 = 0;
    if (base + 3 < n) {
        int4 v = *(const int4*)&deg[base];
        v0 = v.x; v1 = v.y; v2 = v.z; v3 = v.w;
    } else {
        if (base + 0 < n) v0 = deg[base + 0];
        if (base + 1 < n) v1 = deg[base + 1];
        if (base + 2 < n) v2 = deg[base + 2];
        if (base + 3 < n) v3 = deg[base + 3];
    }
    int local = v0 + v1 + v2 + v3;
    s[t] = local;
    __syncthreads();
    for (int off = 1; off < 256; off <<= 1) {
        int x = (t >= off) ? s[t - off] : 0;
        __syncthreads();
        s[t] += x;
        __syncthreads();
    }
    if (t == 255) bsum[blockIdx.x] = s[255];
    int pre = s[t] - local;
    if (base + 3 < n) {
        *(int4*)&excl[base] = make_int4(pre, pre + v0, pre + v0 + v1, pre + v0 + v1 + v2);
    } else {
        if (base + 0 < n) excl[base + 0] = pre;
        if (base + 1 < n) excl[base + 1] = pre + v0;
        if (base + 2 < n) excl[base + 2] = pre + v0 + v1;
        if (base + 3 < n) excl[base + 3] = pre + v0 + v1 + v2;
    }
}

// K4b: single-block exclusive scan of block sums (nb <= 256).
__global__ __launch_bounds__(256) void k_scan_partials(int* __restrict__ bsum, int nb) {
    __shared__ int s[256];
    int t = threadIdx.x;
    int orig = (t < nb) ? bsum[t] : 0;
    s[t] = orig;
    __syncthreads();
    for (int off = 1; off < 256; off <<= 1) {
        int x = (t >= off) ? s[t - off] : 0;
        __syncthreads();
        s[t] += x;
        __syncthreads();
    }
    if (t < nb) bsum[t] = s[t] - orig;  // exclusive
}

// K4c: add scanned block offsets → final exclusive starts in ptr.
__global__ __launch_bounds__(256) void k_scan_add(int* __restrict__ ptr,
                                                  const int* __restrict__ bsum, int n) {
    int t = threadIdx.x;
    int base = blockIdx.x * 1024 + t * 4;
    int add = bsum[blockIdx.x];
    if (base + 3 < n) {
        int4 v = *(int4*)&ptr[base];
        v.x += add; v.y += add; v.z += add; v.w += add;
        *(int4*)&ptr[base] = v;
    } else {
        if (base + 0 < n) ptr[base + 0] += add;
        if (base + 1 < n) ptr[base + 1] += add;
        if (base + 2 < n) ptr[base + 2] += add;
        if (base + 3 < n) ptr[base + 3] += add;
    }
}

// K5: counting-sort fill. ptr[col] advances start→end; srcs[pos] = row.
__global__ __launch_bounds__(256) void k_fill(const int* __restrict__ rows,
                                              const int* __restrict__ cols,
                                              int* __restrict__ ptr,
                                              int* __restrict__ srcs, int nE) {
    int e = blockIdx.x * 256 + threadIdx.x;
    if (e < nE) {
        int pos = atomicAdd(&ptr[cols[e]], 1);
        srcs[pos] = rows[e];
    }
}

// ---------------------------------------------------------------------------
// K6: gather-aggregate. One wave per node, 64 lanes = 64 channels.
// With xws[v] = xw[v]*dis[v]:
//   out[i][c] = dis[i] * ( xws[i][c] + sum_{src in N(i)} xws[src][c] )
// (self-loop term is xws[i] itself — the dis[i] factor comes from the final
//  multiply; do NOT scale it again. That extra *dn was R2's bug.)
__global__ __launch_bounds__(256) void k_gather(const int* __restrict__ ptr,
                                                const int* __restrict__ deg,
                                                const int* __restrict__ srcs,
                                                const float* __restrict__ xws,
                                                float* __restrict__ out,
                                                const float* __restrict__ dis, int n) {
    int c = threadIdx.x & 63;
    int node = blockIdx.x * 4 + (threadIdx.x >> 6);
    if (node >= n) return;

    int end = ptr[node];
    int d = deg[node];
    int start = end - d;
    float dn = dis[node];

    float acc0 = xws[(size_t)node * C_OUT + c];  // self-loop: xws[i], no extra dn
    float acc1 = 0.f;

    for (int b = start; b < end; b += 64) {
        int m = min(64, end - b);
        int sv = (b + c < end) ? srcs[b + c] : 0;
        int j = 0;
        for (; j + 1 < m; j += 2) {
            int s0 = __shfl(sv, j);
            int s1 = __shfl(sv, j + 1);
            acc0 += xws[(size_t)s0 * C_OUT + c];
            acc1 += xws[(size_t)s1 * C_OUT + c];
        }
        if (j < m) {
            int s0 = __shfl(sv, j);
            acc0 += xws[(size_t)s0 * C_OUT + c];
        }
    }
    out[(size_t)node * C_OUT + c] = (acc0 + acc1) * dn;
}

// ---------------------------------------------------------------------------
// K7: per-channel sum and sumsq. stats[0..63]=sum, stats[64..127]=sumsq.
__global__ __launch_bounds__(256) void k_stats(const float* __restrict__ agg,
                                               float* __restrict__ stats, int n) {
    int c = threadIdx.x & 63;
    int sub = threadIdx.x >> 6;
    float s = 0.f, s2 = 0.f;
    for (int node = blockIdx.x * 4 + sub; node < n; node += gridDim.x * 4) {
        float v = agg[(size_t)node * C_OUT + c];
        s += v;
        s2 += v * v;
    }
    __shared__ float red[2][4][64];
    red[0][sub][c] = s;
    red[1][sub][c] = s2;
    __syncthreads();
    if (sub == 0) {
        s  = red[0][0][c] + red[0][1][c] + red[0][2][c] + red[0][3][c];
        s2 = red[1][0][c] + red[1][1][c] + red[1][2][c] + red[1][3][c];
        atomicAdd(&stats[c], s);
        atomicAdd(&stats[64 + c], s2);
    }
}

// ---------------------------------------------------------------------------
// K8: BN normalize + LeakyReLU, float4, in-place. (GCN bias b cancels in BN.)
__global__ __launch_bounds__(256) void k_final(const float* __restrict__ stats,
                                               const float* __restrict__ gamma,
                                               const float* __restrict__ beta,
                                               float* __restrict__ out, int n) {
    int gid = blockIdx.x * 256 + threadIdx.x;
    int total4 = n * (C_OUT / 4);
    if (gid >= total4) return;
    int c4 = (gid & 15) * 4;
    float inv_n = 1.0f / (float)n;
    float4 s  = *(const float4*)&stats[c4];
    float4 s2 = *(const float4*)&stats[64 + c4];
    float4 g4 = *(const float4*)&gamma[c4];
    float4 b4 = *(const float4*)&beta[c4];
    float4 v = ((const float4*)out)[gid];

    float m, var, k, y;
    m = s.x * inv_n; var = s2.x * inv_n - m * m; k = rsqrtf(var + BN_EPS) * g4.x;
    y = (v.x - m) * k + b4.x; v.x = y >= 0.f ? y : LEAKY * y;
    m = s.y * inv_n; var = s2.y * inv_n - m * m; k = rsqrtf(var + BN_EPS) * g4.y;
    y = (v.y - m) * k + b4.y; v.y = y >= 0.f ? y : LEAKY * y;
    m = s.z * inv_n; var = s2.z * inv_n - m * m; k = rsqrtf(var + BN_EPS) * g4.z;
    y = (v.z - m) * k + b4.z; v.z = y >= 0.f ? y : LEAKY * y;
    m = s.w * inv_n; var = s2.w * inv_n - m * m; k = rsqrtf(var + BN_EPS) * g4.w;
    y = (v.w - m) * k + b4.w; v.w = y >= 0.f ? y : LEAKY * y;

    ((float4*)out)[gid] = v;
}

// ---------------------------------------------------------------------------
extern "C" void kernel_launch(void* const* d_in, const int* in_sizes, int n_in,
                              void* d_out, int out_size, void* d_ws, size_t ws_size,
                              hipStream_t stream) {
    const float* x     = (const float*)d_in[0];
    const int*   ei    = (const int*)d_in[1];
    const float* W     = (const float*)d_in[2];
    // d_in[3] = b: cancels in BatchNorm, unused.
    const float* gamma = (const float*)d_in[4];
    const float* beta  = (const float*)d_in[5];
    float* out = (float*)d_out;

    int n  = in_sizes[0] / C_IN;
    int nE = in_sizes[1] / 2;
    const int* rows = ei;
    const int* cols = ei + nE;

    // ws layout (4-byte units):
    // deg[n] | ptr[n] | dis[n] | xws[n*64] | srcs[nE] | bsum[256] | stats[128]
    int*   deg   = (int*)d_ws;
    int*   ptr   = deg + n;
    float* dis   = (float*)(ptr + n);
    float* xws   = dis + n;
    int*   srcs  = (int*)(xws + (size_t)n * C_OUT);
    int*   bsum  = srcs + nE;
    float* stats = (float*)(bsum + 256);

    int nb = (n + 1023) / 1024;  // scan blocks (must be <= 256)

    hipMemsetAsync(deg, 0, (size_t)n * sizeof(int), stream);
    hipMemsetAsync(stats, 0, 2 * C_OUT * sizeof(float), stream);

    k_degree<<<(nE + 255) / 256, 256, 0, stream>>>(cols, deg, nE);
    k_dis<<<(n + 255) / 256, 256, 0, stream>>>(deg, dis, n);
    k_gemm<<<(n + GEMM_NODES - 1) / GEMM_NODES, 256, 0, stream>>>(x, W, dis, xws, n);

    k_scan_block<<<nb, 256, 0, stream>>>(deg, ptr, bsum, n);
    k_scan_partials<<<1, 256, 0, stream>>>(bsum, nb);
    k_scan_add<<<nb, 256, 0, stream>>>(ptr, bsum, n);
    k_fill<<<(nE + 255) / 256, 256, 0, stream>>>(rows, cols, ptr, srcs, nE);

    k_gather<<<(n + 3) / 4, 256, 0, stream>>>(ptr, deg, srcs, xws, out, dis, n);

    k_stats<<<512, 256, 0, stream>>>(out, stats, n);
    k_final<<<(n * (C_OUT / 4) + 255) / 256, 256, 0, stream>>>(stats, gamma, beta, out, n);
}

// Round 4
// 387.810 us; speedup vs baseline: 1.5598x; 1.0969x over previous
//
#include <hip/hip_runtime.h>

#define C_IN 128
#define C_OUT 64
#define BN_EPS 1e-5f
#define LEAKY 0.01f
#define NPART 8          // = #XCDs; blockIdx % 8 assumed round-robin over XCDs
#define FILL_CHUNK 2048  // edges per block (256 thr x 8 iters)

// ---------------------------------------------------------------------------
// K1: in-degree, XCD-partitioned. Block b: partition p=b&7, edge chunk b>>3.
// Only cols in [p*psize,(p+1)*psize) are counted by this block, so each deg
// cache line is only ever touched by one XCD -> atomics stay L2-local.
__global__ __launch_bounds__(256) void k_degree(const int* __restrict__ cols,
                                                int* __restrict__ deg, int nE,
                                                int psize) {
    int p = blockIdx.x & (NPART - 1);
    int base = (blockIdx.x >> 3) * FILL_CHUNK;
    int lo = p * psize, hi = lo + psize;
    int e = min(base + FILL_CHUNK, nE);
    for (int i = base + threadIdx.x; i < e; i += 256) {
        int c = cols[i];
        if (c >= lo && c < hi) atomicAdd(&deg[c], 1);
    }
}

// K2: dis[i] = rsqrt(deg[i] + 1)
__global__ __launch_bounds__(256) void k_dis(const int* __restrict__ deg,
                                             float* __restrict__ dis, int n) {
    int i = blockIdx.x * 256 + threadIdx.x;
    if (i < n) dis[i] = rsqrtf((float)(deg[i] + 1));
}

// ---------------------------------------------------------------------------
// K3: xws = (x @ W) * dis[node]   (prescale folds dis[row] out of the gather
// inner loop). fp32 vector ALU (no fp32 MFMA on CDNA4).
#define GEMM_NODES 32
#define XS_STRIDE 132
__global__ __launch_bounds__(256) void k_gemm(const float* __restrict__ x,
                                              const float* __restrict__ W,
                                              const float* __restrict__ dis,
                                              float* __restrict__ xws, int n) {
    __shared__ float Ws[C_IN * C_OUT];            // 32 KB
    __shared__ float xs[GEMM_NODES * XS_STRIDE];  // 16.5 KB

    const int t = threadIdx.x;
    const int base = blockIdx.x * GEMM_NODES;

    {
        const float4* W4 = (const float4*)W;
        float4* Ws4 = (float4*)Ws;
        #pragma unroll
        for (int j = 0; j < 8; ++j) Ws4[t + j * 256] = W4[t + j * 256];
    }
    {
        const float4* x4 = (const float4*)x;
        #pragma unroll
        for (int j = 0; j < 4; ++j) {
            int i4 = t + j * 256;
            int node = i4 >> 5;
            int kf = i4 & 31;
            float4 v = make_float4(0.f, 0.f, 0.f, 0.f);
            if (base + node < n) v = x4[(size_t)(base + node) * 32 + kf];
            *(float4*)&xs[node * XS_STRIDE + kf * 4] = v;
        }
    }
    __syncthreads();

    const int cg4 = (t >> 4) * 4;
    const int ng  = t & 15;

    float acc[2][4] = {};
    #pragma unroll 8
    for (int k = 0; k < C_IN; k += 4) {
        float4 w0 = *(const float4*)&Ws[(k + 0) * C_OUT + cg4];
        float4 w1 = *(const float4*)&Ws[(k + 1) * C_OUT + cg4];
        float4 w2 = *(const float4*)&Ws[(k + 2) * C_OUT + cg4];
        float4 w3 = *(const float4*)&Ws[(k + 3) * C_OUT + cg4];
        #pragma unroll
        for (int j = 0; j < 2; ++j) {
            float4 xv = *(const float4*)&xs[(ng + 16 * j) * XS_STRIDE + k];
            acc[j][0] += xv.x * w0.x + xv.y * w1.x + xv.z * w2.x + xv.w * w3.x;
            acc[j][1] += xv.x * w0.y + xv.y * w1.y + xv.z * w2.y + xv.w * w3.y;
            acc[j][2] += xv.x * w0.z + xv.y * w1.z + xv.z * w2.z + xv.w * w3.z;
            acc[j][3] += xv.x * w0.w + xv.y * w1.w + xv.z * w2.w + xv.w * w3.w;
        }
    }
    #pragma unroll
    for (int j = 0; j < 2; ++j) {
        int node = base + ng + 16 * j;
        if (node < n) {
            float dn = dis[node];
            *(float4*)&xws[(size_t)node * C_OUT + cg4] =
                make_float4(acc[j][0] * dn, acc[j][1] * dn,
                            acc[j][2] * dn, acc[j][3] * dn);
        }
    }
}

// ---------------------------------------------------------------------------
// CSR build: exclusive scan of deg → ptr (starts), then counting-sort fill
// mutates ptr into segment ENDS (start = end - deg).

__global__ __launch_bounds__(256) void k_scan_block(const int* __restrict__ deg,
                                                    int* __restrict__ excl,
                                                    int* __restrict__ bsum, int n) {
    __shared__ int s[256];
    int t = threadIdx.x;
    int base = blockIdx.x * 1024 + t * 4;
    int v0 = 0, v1 = 0, v2 = 0, v3 = 0;
    if (base + 3 < n) {
        int4 v = *(const int4*)&deg[base];
        v0 = v.x; v1 = v.y; v2 = v.z; v3 = v.w;
    } else {
        if (base + 0 < n) v0 = deg[base + 0];
        if (base + 1 < n) v1 = deg[base + 1];
        if (base + 2 < n) v2 = deg[base + 2];
        if (base + 3 < n) v3 = deg[base + 3];
    }
    int local = v0 + v1 + v2 + v3;
    s[t] = local;
    __syncthreads();
    for (int off = 1; off < 256; off <<= 1) {
        int x = (t >= off) ? s[t - off] : 0;
        __syncthreads();
        s[t] += x;
        __syncthreads();
    }
    if (t == 255) bsum[blockIdx.x] = s[255];
    int pre = s[t] - local;
    if (base + 3 < n) {
        *(int4*)&excl[base] = make_int4(pre, pre + v0, pre + v0 + v1, pre + v0 + v1 + v2);
    } else {
        if (base + 0 < n) excl[base + 0] = pre;
        if (base + 1 < n) excl[base + 1] = pre + v0;
        if (base + 2 < n) excl[base + 2] = pre + v0 + v1;
        if (base + 3 < n) excl[base + 3] = pre + v0 + v1 + v2;
    }
}

__global__ __launch_bounds__(256) void k_scan_partials(int* __restrict__ bsum, int nb) {
    __shared__ int s[256];
    int t = threadIdx.x;
    int orig = (t < nb) ? bsum[t] : 0;
    s[t] = orig;
    __syncthreads();
    for (int off = 1; off < 256; off <<= 1) {
        int x = (t >= off) ? s[t - off] : 0;
        __syncthreads();
        s[t] += x;
        __syncthreads();
    }
    if (t < nb) bsum[t] = s[t] - orig;  // exclusive
}

__global__ __launch_bounds__(256) void k_scan_add(int* __restrict__ ptr,
                                                  const int* __restrict__ bsum, int n) {
    int t = threadIdx.x;
    int base = blockIdx.x * 1024 + t * 4;
    int add = bsum[blockIdx.x];
    if (base + 3 < n) {
        int4 v = *(int4*)&ptr[base];
        v.x += add; v.y += add; v.z += add; v.w += add;
        *(int4*)&ptr[base] = v;
    } else {
        if (base + 0 < n) ptr[base + 0] += add;
        if (base + 1 < n) ptr[base + 1] += add;
        if (base + 2 < n) ptr[base + 2] += add;
        if (base + 3 < n) ptr[base + 3] += add;
    }
}

// K5: counting-sort fill, XCD-partitioned (same scheme as k_degree). All
// atomics on ptr[lo..hi) and stores into srcs[CSR range of partition p] come
// from blocks with the same blockIdx%8 -> one XCD -> lines merge in its L2
// instead of ping-ponging (R3: 105 MB WRITE_SIZE = 64 B/edge).
__global__ __launch_bounds__(256) void k_fill(const int* __restrict__ rows,
                                              const int* __restrict__ cols,
                                              int* __restrict__ ptr,
                                              int* __restrict__ srcs, int nE,
                                              int psize) {
    int p = blockIdx.x & (NPART - 1);
    int base = (blockIdx.x >> 3) * FILL_CHUNK;
    int lo = p * psize, hi = lo + psize;
    int e = min(base + FILL_CHUNK, nE);
    for (int i = base + threadIdx.x; i < e; i += 256) {
        int c = cols[i];
        if (c >= lo && c < hi) {
            int pos = atomicAdd(&ptr[c], 1);
            srcs[pos] = rows[i];
        }
    }
}

// ---------------------------------------------------------------------------
// K6: gather-aggregate. One wave per node, 64 lanes = 64 channels.
// With xws[v] = xw[v]*dis[v]:
//   out[i][c] = dis[i] * ( xws[i][c] + sum_{src in N(i)} xws[src][c] )
__global__ __launch_bounds__(256) void k_gather(const int* __restrict__ ptr,
                                                const int* __restrict__ deg,
                                                const int* __restrict__ srcs,
                                                const float* __restrict__ xws,
                                                float* __restrict__ out,
                                                const float* __restrict__ dis, int n) {
    int c = threadIdx.x & 63;
    int node = blockIdx.x * 4 + (threadIdx.x >> 6);
    if (node >= n) return;

    int end = ptr[node];
    int d = deg[node];
    int start = end - d;
    float dn = dis[node];

    float acc0 = xws[(size_t)node * C_OUT + c];  // self-loop term
    float acc1 = 0.f;

    for (int b = start; b < end; b += 64) {
        int m = min(64, end - b);
        int sv = (b + c < end) ? srcs[b + c] : 0;
        int j = 0;
        for (; j + 1 < m; j += 2) {
            int s0 = __shfl(sv, j);
            int s1 = __shfl(sv, j + 1);
            acc0 += xws[(size_t)s0 * C_OUT + c];
            acc1 += xws[(size_t)s1 * C_OUT + c];
        }
        if (j < m) {
            int s0 = __shfl(sv, j);
            acc0 += xws[(size_t)s0 * C_OUT + c];
        }
    }
    out[(size_t)node * C_OUT + c] = (acc0 + acc1) * dn;
}

// ---------------------------------------------------------------------------
// K7: per-channel sum and sumsq. stats[0..63]=sum, stats[64..127]=sumsq.
__global__ __launch_bounds__(256) void k_stats(const float* __restrict__ agg,
                                               float* __restrict__ stats, int n) {
    int c = threadIdx.x & 63;
    int sub = threadIdx.x >> 6;
    float s = 0.f, s2 = 0.f;
    for (int node = blockIdx.x * 4 + sub; node < n; node += gridDim.x * 4) {
        float v = agg[(size_t)node * C_OUT + c];
        s += v;
        s2 += v * v;
    }
    __shared__ float red[2][4][64];
    red[0][sub][c] = s;
    red[1][sub][c] = s2;
    __syncthreads();
    if (sub == 0) {
        s  = red[0][0][c] + red[0][1][c] + red[0][2][c] + red[0][3][c];
        s2 = red[1][0][c] + red[1][1][c] + red[1][2][c] + red[1][3][c];
        atomicAdd(&stats[c], s);
        atomicAdd(&stats[64 + c], s2);
    }
}

// ---------------------------------------------------------------------------
// K8: BN normalize + LeakyReLU, float4, in-place. (GCN bias b cancels in BN.)
__global__ __launch_bounds__(256) void k_final(const float* __restrict__ stats,
                                               const float* __restrict__ gamma,
                                               const float* __restrict__ beta,
                                               float* __restrict__ out, int n) {
    int gid = blockIdx.x * 256 + threadIdx.x;
    int total4 = n * (C_OUT / 4);
    if (gid >= total4) return;
    int c4 = (gid & 15) * 4;
    float inv_n = 1.0f / (float)n;
    float4 s  = *(const float4*)&stats[c4];
    float4 s2 = *(const float4*)&stats[64 + c4];
    float4 g4 = *(const float4*)&gamma[c4];
    float4 b4 = *(const float4*)&beta[c4];
    float4 v = ((const float4*)out)[gid];

    float m, var, k, y;
    m = s.x * inv_n; var = s2.x * inv_n - m * m; k = rsqrtf(var + BN_EPS) * g4.x;
    y = (v.x - m) * k + b4.x; v.x = y >= 0.f ? y : LEAKY * y;
    m = s.y * inv_n; var = s2.y * inv_n - m * m; k = rsqrtf(var + BN_EPS) * g4.y;
    y = (v.y - m) * k + b4.y; v.y = y >= 0.f ? y : LEAKY * y;
    m = s.z * inv_n; var = s2.z * inv_n - m * m; k = rsqrtf(var + BN_EPS) * g4.z;
    y = (v.z - m) * k + b4.z; v.z = y >= 0.f ? y : LEAKY * y;
    m = s.w * inv_n; var = s2.w * inv_n - m * m; k = rsqrtf(var + BN_EPS) * g4.w;
    y = (v.w - m) * k + b4.w; v.w = y >= 0.f ? y : LEAKY * y;

    ((float4*)out)[gid] = v;
}

// ---------------------------------------------------------------------------
extern "C" void kernel_launch(void* const* d_in, const int* in_sizes, int n_in,
                              void* d_out, int out_size, void* d_ws, size_t ws_size,
                              hipStream_t stream) {
    const float* x     = (const float*)d_in[0];
    const int*   ei    = (const int*)d_in[1];
    const float* W     = (const float*)d_in[2];
    // d_in[3] = b: cancels in BatchNorm, unused.
    const float* gamma = (const float*)d_in[4];
    const float* beta  = (const float*)d_in[5];
    float* out = (float*)d_out;

    int n  = in_sizes[0] / C_IN;
    int nE = in_sizes[1] / 2;
    const int* rows = ei;
    const int* cols = ei + nE;

    // ws layout (4-byte units):
    // deg[n] | ptr[n] | dis[n] | xws[n*64] | srcs[nE] | bsum[256] | stats[128]
    int*   deg   = (int*)d_ws;
    int*   ptr   = deg + n;
    float* dis   = (float*)(ptr + n);
    float* xws   = dis + n;
    int*   srcs  = (int*)(xws + (size_t)n * C_OUT);
    int*   bsum  = srcs + nE;
    float* stats = (float*)(bsum + 256);

    int nb = (n + 1023) / 1024;       // scan blocks (must be <= 256)
    int psize = (n + NPART - 1) / NPART;
    int nchunks = (nE + FILL_CHUNK - 1) / FILL_CHUNK;

    hipMemsetAsync(deg, 0, (size_t)n * sizeof(int), stream);
    hipMemsetAsync(stats, 0, 2 * C_OUT * sizeof(float), stream);

    k_degree<<<nchunks * NPART, 256, 0, stream>>>(cols, deg, nE, psize);
    k_dis<<<(n + 255) / 256, 256, 0, stream>>>(deg, dis, n);
    k_gemm<<<(n + GEMM_NODES - 1) / GEMM_NODES, 256, 0, stream>>>(x, W, dis, xws, n);

    k_scan_block<<<nb, 256, 0, stream>>>(deg, ptr, bsum, n);
    k_scan_partials<<<1, 256, 0, stream>>>(bsum, nb);
    k_scan_add<<<nb, 256, 0, stream>>>(ptr, bsum, n);
    k_fill<<<nchunks * NPART, 256, 0, stream>>>(rows, cols, ptr, srcs, nE, psize);

    k_gather<<<(n + 3) / 4, 256, 0, stream>>>(ptr, deg, srcs, xws, out, dis, n);

    k_stats<<<512, 256, 0, stream>>>(out, stats, n);
    k_final<<<(n * (C_OUT / 4) + 255) / 256, 256, 0, stream>>>(stats, gamma, beta, out, n);
}